// Round 7
// baseline (116.572 us; speedup 1.0000x reference)
//
#include <hip/hip_runtime.h>

// QuinticHermiteSpline: 2^24 fp32 queries, 1024 uniform knots in [0,1].
// R11: two-pipe model. R8->R9 showed in-flight bytes 9->56 KB/CU moved BW
//     only 4.4->5.0 TB/s => MLP stopped being the limiter; layout (R10) was
//     neutral. Refined arithmetic: LDS pipe busy ~= 3328 wave-instrs/CU
//     (12 b64 gathers + 1 ring b128 per item) x 7-12 cyc (issue + random-
//     gather bank imbalance) ~= 12-16 us/CU -- co-critical with the 20.4 us
//     HBM floor. Imperfect overlap of two near-critical pipes = ~25 us.
//   Changes vs R10 (ring/pipeline/layout unchanged):
//   - Table gather 13 -> 9 LDS issues/item: cA float4 {c5,c4,c3,c2} via
//     ds_read_b128 + cB float2 {c1,c0} via ds_read_b64. (R5's reverse test
//     was run when LDS was fully hidden at ~40us; null doesn't transfer.)
//   - Stores: regular (not nontemporal). NT streams to DRAM with urgency,
//     contending with reads; normal stores absorb into L2 (fills hit
//     6.2 TB/s this way) and write back in controller-friendly bursts.
//     vmcnt bookkeeping identical (stores still count, retire no later).
// Prediction: spline ~25.5 -> 22-23.5 us; dur_us ~109-111. If neutral,
// declare the two-pipe ceiling (kernel ~10-15% over naive HBM floor).

#define N_KNOTS 1024
#define N_INT   1023
#define RING_D  4

typedef float vfloat4 __attribute__((ext_vector_type(4)));

#define AS1 __attribute__((address_space(1)))
#define AS3 __attribute__((address_space(3)))

// Table: cA[i] = {c5,c4,c3,c2} (b128), cB[i] = {c1,c0} (b64). 24552 B.
__device__ __forceinline__ float eval_one(float xq,
                                          const float4* __restrict__ cA,
                                          const float2* __restrict__ cB) {
    float s = xq * 1023.0f;
    int idx = (int)s;
    idx = min(max(idx, 0), N_INT - 1);
    float t = s - (float)idx;
    float4 a = cA[idx];                // ds_read_b128
    float2 b = cB[idx];                // ds_read_b64
    float v = fmaf(a.x, t, a.y);
    v = fmaf(v, t, a.z);
    v = fmaf(v, t, a.w);
    v = fmaf(v, t, b.x);
    v = fmaf(v, t, b.y);
    return v;
}

__global__ __launch_bounds__(512, 4) void quintic_spline_fused(
    const float* __restrict__ x_new,
    const float* __restrict__ knots,
    const float* __restrict__ fv,      // [3,1024]: y, dy, ddy
    float* __restrict__ out,
    int n4)
{
    __shared__ __align__(16) float4 cA[N_INT];            // 16368 B
    __shared__ float2 cB[N_INT];                          //  8184 B
    __shared__ __align__(16) float ring[8][RING_D][256];  // 32768 B -> 57320 B

    const int w    = threadIdx.x >> 6;         // wave id (lane-uniform)
    const int lane = threadIdx.x & 63;

    const bool fast = (n4 == (1 << 22)) && (gridDim.x == 512)
                      && (blockDim.x == 512);

    if (fast) {
        // Ring prologue FIRST: its HBM latency hides under the table build;
        // build loads queue behind in the same in-order FIFO.
        uint32_t base_b = ((uint32_t)blockIdx.x * 8192u
                           + (uint32_t)threadIdx.x) * 16u;
#pragma unroll
        for (int k = 0; k < RING_D; ++k) {
            const float* gsrc =
                (const float*)((const char*)x_new + base_b + (uint32_t)k * 8192u);
            __builtin_amdgcn_global_load_lds(
                (AS1 const unsigned*)(const void*)gsrc,
                (AS3 unsigned*)(void*)&ring[w][k][0], 16, 0, 0);
        }
    }

    {
        const float* __restrict__ y   = fv;
        const float* __restrict__ dy  = fv + N_KNOTS;
        const float* __restrict__ ddy = fv + 2 * N_KNOTS;
        // Per-block table build: 1023 intervals, 512 threads -> 2 each.
        for (int i = threadIdx.x; i < N_INT; i += 512) {
            float xl   = knots[i];
            float h    = knots[i + 1] - xl;
            float yl   = y[i],   yr   = y[i + 1];
            float dyl  = dy[i],  dyr  = dy[i + 1];
            float ddyl = ddy[i], ddyr = ddy[i + 1];
            float dY = yr - yl;
            float h2 = 0.5f * h * h;
            float c5 =   6.0f * dY - 3.0f * h * (dyl + dyr)               + h2 * (ddyr - ddyl);
            float c4 = -15.0f * dY + h * (8.0f * dyl + 7.0f * dyr)        - h2 * (2.0f * ddyr - 3.0f * ddyl);
            float c3 =  10.0f * dY - 2.0f * h * (3.0f * dyl + 2.0f * dyr) + h2 * (ddyr - 3.0f * ddyl);
            cA[i] = make_float4(c5, c4, c3, h2 * ddyl);
            cB[i] = make_float2(h * dyl, yl);
        }
    }
    __syncthreads();
    // Barrier drains all vmem (prologue completed into LDS) -> vmcnt = 0.

    if (fast) {
        // Block-contiguous region: 8192 float4 per block; iter k covers
        // float4 indices base4 + k*512 (8 KB cursor step per block).
        uint32_t base4 = (uint32_t)blockIdx.x * 8192u + (uint32_t)threadIdx.x;
        vfloat4* __restrict__ o4 = (vfloat4*)out;

#pragma unroll
        for (int k = 0; k < 16; ++k) {
            // Younger-than-L_k in this wave's FIFO (iter j appends
            // [L_{j+4}, S_j] after the barrier):
            //   stores: min(k,4); loads: min(3, 15-k). Steady 7, never 0.
            const int N = (k < 4 ? k : 4) + ((15 - k) < 3 ? (15 - k) : 3);
            asm volatile("s_waitcnt vmcnt(%0)" :: "i"(N) : "memory");

            // Consume slot k%4 (ordered after the wait by the clobber).
            vfloat4 xv = *(const vfloat4*)&ring[w][k & (RING_D - 1)][lane << 2];

            // Refill the just-read slot immediately (LDS write lands at data
            // return, far after the ds_read completes).
            if (k + RING_D < 16) {
                const float* gsrc =
                    x_new + (size_t)(base4 + (uint32_t)(k + RING_D) * 512u) * 4;
                __builtin_amdgcn_global_load_lds(
                    (AS1 const unsigned*)(const void*)gsrc,
                    (AS3 unsigned*)(void*)&ring[w][k & (RING_D - 1)][0],
                    16, 0, 0);
            }
            __builtin_amdgcn_sched_barrier(0);   // pin refill before eval/store

            vfloat4 r;
            r.x = eval_one(xv.x, cA, cB);
            r.y = eval_one(xv.y, cA, cB);
            r.z = eval_one(xv.z, cA, cB);
            r.w = eval_one(xv.w, cA, cB);
            // Regular store: absorb into L2, lazy writeback (NT contended
            // with the read stream; fills reach 6.2 TB/s via this path).
            o4[base4 + (uint32_t)k * 512u] = r;
        }
    } else {
        // Generic fallback (any n4, any grid).
        const vfloat4* __restrict__ x4 = (const vfloat4*)x_new;
        vfloat4* __restrict__ o4 = (vfloat4*)out;
        int tid = blockIdx.x * blockDim.x + threadIdx.x;
        int stride = gridDim.x * blockDim.x;
        for (int i = tid; i < n4; i += stride) {
            vfloat4 xv = __builtin_nontemporal_load(&x4[i]);
            vfloat4 r;
            r.x = eval_one(xv.x, cA, cB);
            r.y = eval_one(xv.y, cA, cB);
            r.z = eval_one(xv.z, cA, cB);
            r.w = eval_one(xv.w, cA, cB);
            o4[i] = r;
        }
    }
}

extern "C" void kernel_launch(void* const* d_in, const int* in_sizes, int n_in,
                              void* d_out, int out_size, void* d_ws, size_t ws_size,
                              hipStream_t stream) {
    const float* x_new = (const float*)d_in[0];
    const float* knots = (const float*)d_in[1];
    const float* fv    = (const float*)d_in[2];
    float* out = (float*)d_out;

    int n = in_sizes[0];          // 16,777,216
    int n4 = n >> 2;              // 4,194,304 = 512 * 8192

    // 512 blocks x 512 threads: exactly 2 blocks/CU (57.3 KB LDS each),
    // 16 waves/CU.
    hipLaunchKernelGGL(quintic_spline_fused, dim3(512), dim3(512), 0, stream,
                       x_new, knots, fv, out, n4);
}

// Round 9
// 114.202 us; speedup vs baseline: 1.0208x; 1.0208x over previous
//
#include <hip/hip_runtime.h>

// QuinticHermiteSpline: 2^24 fp32 queries, 1024 uniform knots in [0,1].
// R13 == R12 resubmitted verbatim (previous round died in the broker:
//     "MI355X container failed twice" -- the kernel never executed, so the
//     phase-stagger hypothesis is still untested).
// R12: revert R11 (regression: regular stores de-sequence the DRAM write
//     stream via L2 eviction order; 113.0 -> 116.6) back to the measured
//     best R10 structure (3x float2 table via ds_read_b64, NT stores),
//     plus ONE new lever: wave-phase stagger.
//   Theory state: MLP exonerated (R9: 56KB/CU in flight -> +0.5 TB/s only),
//     DRAM footprint exonerated (R10 neutral), LDS pipe exonerated (ring
//     ADDED LDS traffic yet beat the register pipeline, R10 25.5 vs R8 29),
//     store path matters only negatively (R11). All per-pipe busy times
//     (stream 20.4us, LDS 10-15us, VALU ~5us) < observed 25.5us. Remaining
//     candidate: LOCKSTEP PHASE COLLISION -- the post-build barrier releases
//     16 identical waves/CU that hit the gather phase simultaneously (LDS
//     slammed, VMEM idle), then the issue/store phase simultaneously. 50-60%
//     average pipes serialize during bursts.
//   Fix: wave w consumes its 16 items in rotated order m(k) = (k + 2w) & 15.
//     Same ring slots, same vmcnt FIFO (count derivation is address-free);
//     phases across waves de-correlate. Zero added instructions.
// Prediction: spline 25.5 -> 22-23us (dur ~110-111.5). If ~113 (neutral),
// declare the ceiling next round.

#define N_KNOTS 1024
#define N_INT   1023
#define RING_D  4

typedef float vfloat4 __attribute__((ext_vector_type(4)));

#define AS1 __attribute__((address_space(1)))
#define AS3 __attribute__((address_space(3)))

// cT layout (contiguous LDS block, 3*1023 float2 = 24552 B):
//   cT[i]            = {c5, c4}
//   cT[N_INT + i]    = {c3, c2}        (c2 = h2*ddyl)
//   cT[2*N_INT + i]  = {c1, c0}        (c1 = h*dyl, c0 = yl)
__device__ __forceinline__ float eval_one(float xq, const float2* cT) {
    float s = xq * 1023.0f;
    int idx = (int)s;
    idx = min(max(idx, 0), N_INT - 1);
    float t = s - (float)idx;
    float2 a = cT[idx];                // ds_read_b64, offset:0
    float2 b = cT[N_INT + idx];        // ds_read_b64, offset:8184
    float2 c = cT[2 * N_INT + idx];    // ds_read_b64, offset:16368
    float v = fmaf(a.x, t, a.y);
    v = fmaf(v, t, b.x);
    v = fmaf(v, t, b.y);
    v = fmaf(v, t, c.x);
    v = fmaf(v, t, c.y);
    return v;
}

__global__ __launch_bounds__(512, 4) void quintic_spline_fused(
    const float* __restrict__ x_new,
    const float* __restrict__ knots,
    const float* __restrict__ fv,      // [3,1024]: y, dy, ddy
    float* __restrict__ out,
    int n4)
{
    __shared__ float2 cT[3 * N_INT];                      // 24552 B
    __shared__ __align__(16) float ring[8][RING_D][256];  // 32768 B -> 57320 B

    const int w    = threadIdx.x >> 6;         // wave id (lane-uniform)
    const int lane = threadIdx.x & 63;
    const int rot  = w << 1;                   // per-wave item rotation

    const bool fast = (n4 == (1 << 22)) && (gridDim.x == 512)
                      && (blockDim.x == 512);

    if (fast) {
        // Ring prologue FIRST: HBM latency hides under the table build;
        // build loads queue behind in the same in-order FIFO. Prologue
        // stages this wave's items m(0..3) into slots 0..3.
        uint32_t base4 = (uint32_t)blockIdx.x * 8192u + (uint32_t)threadIdx.x;
#pragma unroll
        for (int k = 0; k < RING_D; ++k) {
            uint32_t m = (uint32_t)((k + rot) & 15);
            const float* gsrc = x_new + (size_t)(base4 + m * 512u) * 4;
            __builtin_amdgcn_global_load_lds(
                (AS1 const unsigned*)(const void*)gsrc,
                (AS3 unsigned*)(void*)&ring[w][k][0], 16, 0, 0);
        }
    }

    {
        const float* __restrict__ y   = fv;
        const float* __restrict__ dy  = fv + N_KNOTS;
        const float* __restrict__ ddy = fv + 2 * N_KNOTS;
        // Per-block table build: 1023 intervals, 512 threads -> 2 each.
        for (int i = threadIdx.x; i < N_INT; i += 512) {
            float xl   = knots[i];
            float h    = knots[i + 1] - xl;
            float yl   = y[i],   yr   = y[i + 1];
            float dyl  = dy[i],  dyr  = dy[i + 1];
            float ddyl = ddy[i], ddyr = ddy[i + 1];
            float dY = yr - yl;
            float h2 = 0.5f * h * h;
            float c5 =   6.0f * dY - 3.0f * h * (dyl + dyr)               + h2 * (ddyr - ddyl);
            float c4 = -15.0f * dY + h * (8.0f * dyl + 7.0f * dyr)        - h2 * (2.0f * ddyr - 3.0f * ddyl);
            float c3 =  10.0f * dY - 2.0f * h * (3.0f * dyl + 2.0f * dyr) + h2 * (ddyr - 3.0f * ddyl);
            cT[i]             = make_float2(c5, c4);
            cT[N_INT + i]     = make_float2(c3, h2 * ddyl);
            cT[2 * N_INT + i] = make_float2(h * dyl, yl);
        }
    }
    __syncthreads();
    // Barrier drains all vmem (prologue completed into LDS) -> vmcnt = 0.

    if (fast) {
        // Block-contiguous region: 8192 float4 per block. Wave w walks its
        // 16 items in rotated order m(k) = (k + 2w) & 15 (bijection).
        uint32_t base4 = (uint32_t)blockIdx.x * 8192u + (uint32_t)threadIdx.x;
        vfloat4* __restrict__ o4 = (vfloat4*)out;

#pragma unroll
        for (int k = 0; k < 16; ++k) {
            // Younger-than-L_k in this wave's FIFO (iter j appends
            // [L_{j+4}, S_j] after the barrier):
            //   stores: min(k,4); loads: min(3, 15-k). Steady 7, never 0.
            // Address rotation does not enter the count.
            const int N = (k < 4 ? k : 4) + ((15 - k) < 3 ? (15 - k) : 3);
            asm volatile("s_waitcnt vmcnt(%0)" :: "i"(N) : "memory");

            // Consume slot k%4 = item m(k) (ordered after wait by clobber).
            vfloat4 xv = *(const vfloat4*)&ring[w][k & (RING_D - 1)][lane << 2];

            // Refill the just-read slot with item m(k+4).
            if (k + RING_D < 16) {
                uint32_t m = (uint32_t)((k + RING_D + rot) & 15);
                const float* gsrc = x_new + (size_t)(base4 + m * 512u) * 4;
                __builtin_amdgcn_global_load_lds(
                    (AS1 const unsigned*)(const void*)gsrc,
                    (AS3 unsigned*)(void*)&ring[w][k & (RING_D - 1)][0],
                    16, 0, 0);
            }
            __builtin_amdgcn_sched_barrier(0);   // pin refill before eval/store

            vfloat4 r;
            r.x = eval_one(xv.x, cT);
            r.y = eval_one(xv.y, cT);
            r.z = eval_one(xv.z, cT);
            r.w = eval_one(xv.w, cT);
            uint32_t mk = (uint32_t)((k + rot) & 15);
            __builtin_nontemporal_store(r, &o4[base4 + mk * 512u]);
        }
    } else {
        // Generic fallback (any n4, any grid).
        const vfloat4* __restrict__ x4 = (const vfloat4*)x_new;
        vfloat4* __restrict__ o4 = (vfloat4*)out;
        int tid = blockIdx.x * blockDim.x + threadIdx.x;
        int stride = gridDim.x * blockDim.x;
        for (int i = tid; i < n4; i += stride) {
            vfloat4 xv = __builtin_nontemporal_load(&x4[i]);
            vfloat4 r;
            r.x = eval_one(xv.x, cT);
            r.y = eval_one(xv.y, cT);
            r.z = eval_one(xv.z, cT);
            r.w = eval_one(xv.w, cT);
            __builtin_nontemporal_store(r, &o4[i]);
        }
    }
}

extern "C" void kernel_launch(void* const* d_in, const int* in_sizes, int n_in,
                              void* d_out, int out_size, void* d_ws, size_t ws_size,
                              hipStream_t stream) {
    const float* x_new = (const float*)d_in[0];
    const float* knots = (const float*)d_in[1];
    const float* fv    = (const float*)d_in[2];
    float* out = (float*)d_out;

    int n = in_sizes[0];          // 16,777,216
    int n4 = n >> 2;              // 4,194,304 = 512 * 8192

    // 512 blocks x 512 threads: exactly 2 blocks/CU (57.3 KB LDS each),
    // 16 waves/CU.
    hipLaunchKernelGGL(quintic_spline_fused, dim3(512), dim3(512), 0, stream,
                       x_new, knots, fv, out, n4);
}